// Round 4
// baseline (275.811 us; speedup 1.0000x reference)
//
#include <hip/hip_runtime.h>
#include <math.h>

#define N_TS 4096
#define SEQ  168
#define HOR  24
#define T_ALL 192
#define F_INP 32
#define HID  64
#define NROW 192            // compacted gate rows: i(64) g(64) o(64)
#define NB_B (N_TS / 16)    // 256 autoregressive blocks (16 series each)
#define NT_B ((N_TS * SEQ) / 64)   // 10752 teacher blocks (64 instances each)
#define L2E  1.44269504089f
#define W16F_L1  6144       // half-offset of standard layer-1 weights (AR path)
#define W16F_L1P 18432      // half-offset of PERMUTED layer-1 weights (teacher)

typedef _Float16 half8  __attribute__((ext_vector_type(8)));
typedef _Float16 half4  __attribute__((ext_vector_type(4)));
typedef float    floatx4 __attribute__((ext_vector_type(4)));

__device__ __forceinline__ float fexp(float x)  { return __expf(x); }
__device__ __forceinline__ float ex2(float x)   { return __builtin_amdgcn_exp2f(x); }
__device__ __forceinline__ float frcp(float x)  { return __builtin_amdgcn_rcpf(x); }
__device__ __forceinline__ float softplus_(float x) { return (x > 15.0f) ? x : __logf(1.0f + fexp(x)); }

// Gates arrive PRESCALED: i,o rows x(-log2e); g rows x(-2*log2e) — folded into
// weights/biases, so every sigmoid/tanh exp is a bare v_exp (2^x).
__device__ __forceinline__ float lstm_h(float ip, float gp, float op) {
    const float Ei = ex2(ip);
    const float Eg = ex2(gp);
    const float cc = (1.0f - Eg) * frcp((1.0f + Ei) * (1.0f + Eg));
    const float Ec = ex2(cc * (-2.0f * L2E));
    const float Eo = ex2(op);
    return (1.0f - Ec) * frcp((1.0f + Ec) * (1.0f + Eo));
}

__device__ __forceinline__ half8 cvt8(const float4 a, const float4 b) {
    half8 v;
    v[0]=(_Float16)a.x; v[1]=(_Float16)a.y; v[2]=(_Float16)a.z; v[3]=(_Float16)a.w;
    v[4]=(_Float16)b.x; v[5]=(_Float16)b.y; v[6]=(_Float16)b.z; v[7]=(_Float16)b.w;
    return v;
}

// ---------------------------------------------------------------------------
// prep: compacted (f dropped), PRESCALED weights in k-chunked fragment layout
//   layer 0 (x-cols only, k<32): W16f[(kb*192+row)*8+kp], kb in [0,4)
//   layer 1 standard (AR path):  W16f[W16F_L1  + (kb*192+row)*8+kp], k = hid
//   layer 1 permuted (teacher):  W16f[W16F_L1P + (kb*192+row)*8+kp], k = pi(hid)
//     pi: k=q*8+2*jt+e     <-> hid=jt*16+q*4+e      (k < 32)
//         k=32+q*8+2*jt+e  <-> hid=jt*16+q*4+2+e    (k >= 32)
//   so the teacher's own L0 output registers ARE its L1 B-fragment (no exchange).
// Rank-1 embed fold (prescaled): wy1 = W1[:,32:]@W_embed ; b1c = b1 + W1[:,32:]@b_embed.
// ---------------------------------------------------------------------------
__global__ __launch_bounds__(256) void prep(
    const float* __restrict__ W_ih, const float* __restrict__ b_ih,
    const float* __restrict__ b_hh,
    const float* __restrict__ W_embed, const float* __restrict__ b_embed,
    _Float16* __restrict__ W16f, float* __restrict__ bsum,
    float* __restrict__ wy1, float* __restrict__ b1c)
{
    const int idx = blockIdx.x * 256 + threadIdx.x;
    // layer 0: x-cols only
    for (int i = idx; i < 4 * NROW * 8; i += gridDim.x * 256) {
        const int kp  = i & 7;
        const int row = (i >> 3) % NROW;
        const int kb  = (i >> 3) / NROW;                   // 0..3 -> k = kb*8+kp < 32
        const int sr  = (row < 64) ? row : row + 64;       // skip dead f rows
        const float sc = (row >= 64 && row < 128) ? (-2.0f * L2E) : (-L2E);
        W16f[i] = (_Float16)(W_ih[sr * HID + kb * 8 + kp] * sc);
    }
    // layer 1 standard (k = hid identity)
    for (int i = idx; i < 8 * NROW * 8; i += gridDim.x * 256) {
        const int kp  = i & 7;
        const int row = (i >> 3) % NROW;
        const int kb  = (i >> 3) / NROW;                   // 0..7
        const int sr  = (row < 64) ? row : row + 64;
        const float sc = (row >= 64 && row < 128) ? (-2.0f * L2E) : (-L2E);
        W16f[W16F_L1 + i] = (_Float16)(W_ih[(256 + sr) * HID + kb * 8 + kp] * sc);
    }
    // layer 1 permuted (teacher): column hid = pi^{-1}(k)
    for (int i = idx; i < 8 * NROW * 8; i += gridDim.x * 256) {
        const int kp  = i & 7;
        const int row = (i >> 3) % NROW;
        const int kb  = (i >> 3) / NROW;
        const int k   = kb * 8 + kp;                       // logical k
        const int kk  = k & 31;
        const int d   = (kk >> 1) & 3;                     // jt
        const int q   = kk >> 3;                           // producer quad
        const int e   = kk & 1;
        const int hid = d * 16 + q * 4 + ((k >> 5) << 1) + e;
        const int sr  = (row < 64) ? row : row + 64;
        const float sc = (row >= 64 && row < 128) ? (-2.0f * L2E) : (-L2E);
        W16f[W16F_L1P + i] = (_Float16)(W_ih[(256 + sr) * HID + hid] * sc);
    }
    for (int i = idx; i < 2 * NROW; i += gridDim.x * 256) {
        const int r = i % NROW;
        const int l = i / NROW;
        const int sr = (r < 64) ? r : r + 64;
        const float sc = (r >= 64 && r < 128) ? (-2.0f * L2E) : (-L2E);
        bsum[i] = (b_ih[l * 256 + sr] + b_hh[l * 256 + sr]) * sc;
    }
    if (idx < NROW) {
        const int sr = (idx < 64) ? idx : idx + 64;
        const float sc = (idx >= 64 && idx < 128) ? (-2.0f * L2E) : (-L2E);
        const float* wrow = W_ih + sr * HID + 32;          // layer 0, cols 32..63
        float s1 = 0.f, s2 = 0.f;
        #pragma unroll
        for (int k = 0; k < 32; ++k) {
            s1 = fmaf(wrow[k], W_embed[k], s1);
            s2 = fmaf(wrow[k], b_embed[k], s2);
        }
        wy1[idx] = s1 * sc;
        b1c[idx] = (b_ih[sr] + b_hh[sr] + s2) * sc;
    }
}

// ---------------------------------------------------------------------------
// fused, 256-thread blocks (4 waves):
//  blocks [0, NB_B): autoregressive path — proven 16-series form, persistent
//   register fragments, XOR-swizzled slab, 2 barriers/step. Unchanged (r3).
//  blocks [NB_B, ...): teacher path, NO LDS, NO BARRIERS: weight fragments read
//   directly from global (L1/L2 broadcast — all blocks read the same 36 KB).
//   h1 -> L1 exchange is free via pi-permuted weights (register-local).
//   Each wave is a fully independent stream; only cross-lane ops are 2 shfls.
//  LDS union = 4 KB (AR slab only) -> 8 blocks/CU (32 waves/CU, 100% ceiling).
// ---------------------------------------------------------------------------
__global__ __launch_bounds__(256, 6) void fused(
    const float* __restrict__ X,
    const float* __restrict__ y,
    const float* __restrict__ Xf,
    const float* __restrict__ W_embed,
    const float* __restrict__ b_embed,
    const _Float16* __restrict__ W16f,
    const float* __restrict__ bsum,
    const float* __restrict__ wy1,
    const float* __restrict__ b1c,
    const float* __restrict__ W_mu,
    const float* __restrict__ b_mu,
    const float* __restrict__ W_sigma,
    const float* __restrict__ b_sigma,
    float* __restrict__ out)
{
    __shared__ struct __align__(16) {
        _Float16 slab[16 * 64]; float partm[16][4]; float parts[16][4];
        float wyb[NROW]; float b1cb[NROW];
    } sh;                                                            // 4096 B

    const int tid = threadIdx.x;
    float* mu_out = out + (size_t)N_TS * HOR;
    float* sg_out = mu_out + (size_t)N_TS * T_ALL;

    if (blockIdx.x < NB_B) {
        // =================== autoregressive path (4 waves) ===================
        __builtin_amdgcn_s_setprio(1);           // beat co-resident teacher waves
        const int w    = tid >> 6;
        const int lane = tid & 63;
        const int quad = lane >> 4;
        const int ln   = lane & 15;
        const int n0   = blockIdx.x * 16;

        if (tid < NROW) {
            sh.wyb[tid]  = wy1[tid];
            sh.b1cb[tid] = b1c[tid];
        }

        // persistent register fragments (wave w owns row-tiles rt = j*4+w)
        half8 B1[3];        // W1 rows, k<32 (embed cols via rank-1 fold)
        half8 B2[3][2];     // W2 rows, full k (STANDARD layout)
        float bias2[3];
        #pragma unroll
        for (int j = 0; j < 3; ++j) {
            const int rt = j * 4 + w;
            B1[j] = *(const half8*)(W16f + ((size_t)quad * NROW + rt * 16 + ln) * 8);
            #pragma unroll
            for (int kt = 0; kt < 2; ++kt)
                B2[j][kt] = *(const half8*)(W16f + W16F_L1 + ((size_t)(kt * 4 + quad) * NROW + rt * 16 + ln) * 8);
            bias2[j] = bsum[NROW + rt * 16 + ln];
        }
        const float wmu = W_mu[w * 16 + ln], wsg = W_sigma[w * 16 + ln];
        const float bmu = b_mu[0], bsg = b_sigma[0];

        // bootstrap inputs: t = 167
        const float* xfp = Xf + (size_t)(n0 + ln) * HOR * F_INP + quad * 8;
        float4 xa, xb;
        {
            const float* xp = X + ((size_t)(n0 + ln) * SEQ + (SEQ - 1)) * F_INP + quad * 8;
            xa = *(const float4*)xp;
            xb = *(const float4*)(xp + 4);
        }
        float ycur = y[(size_t)(n0 + ln) * SEQ + (SEQ - 1)];
        __syncthreads();                         // wyb/b1cb visible

        #pragma unroll 1
        for (int it = 0; it <= HOR + 1; ++it) {
            if (it > 0) {
                // finalize step k = it-1 (redundant per-lane, bit-identical)
                const int k = it - 1;
                const float4 m4 = *(const float4*)sh.partm[ln];
                const float4 s4 = *(const float4*)sh.parts[ln];
                const float mu = (m4.x + m4.y) + (m4.z + m4.w) + bmu;
                const float sg = softplus_((s4.x + s4.y) + (s4.z + s4.w) + bsg) + 1e-6f;
                const float d  = ycur - mu;
                const float is = frcp(sg);
                const float lik = 0.39894228040143267f * is * fexp(-0.5f * d * d * is * is);
                if (k > 0 && w == 0 && quad == 0) {
                    const int nn = n0 + ln;
                    const int t  = SEQ + k - 1;
                    mu_out[(size_t)nn * T_ALL + t] = mu;
                    sg_out[(size_t)nn * T_ALL + t] = sg;
                    if (k < HOR) out[(size_t)nn * HOR + k] = lik;
                }
                ycur = lik;
            }
            if (it > HOR) break;

            // ---- compute step it (input carry = ycur) ----
            const half8 xf0 = cvt8(xa, xb);
            if (it < HOR) {                      // next iter uses Xf step it
                xa = *(const float4*)(xfp + it * F_INP);
                xb = *(const float4*)(xfp + it * F_INP + 4);
            }

            // layer 1: 3 MFMAs; C row = unit-in-tile (quad*4+r), col = series(ln)
            floatx4 t0 = *(const floatx4*)(sh.b1cb + 0 * 64 + w * 16 + quad * 4);
            floatx4 t1 = *(const floatx4*)(sh.b1cb + 1 * 64 + w * 16 + quad * 4);
            floatx4 t2 = *(const floatx4*)(sh.b1cb + 2 * 64 + w * 16 + quad * 4);
            t0 = __builtin_amdgcn_mfma_f32_16x16x32_f16(B1[0], xf0, t0, 0, 0, 0);
            t1 = __builtin_amdgcn_mfma_f32_16x16x32_f16(B1[1], xf0, t1, 0, 0, 0);
            t2 = __builtin_amdgcn_mfma_f32_16x16x32_f16(B1[2], xf0, t2, 0, 0, 0);

            const floatx4 wy0  = *(const floatx4*)(sh.wyb + 0 * 64 + w * 16 + quad * 4);
            const floatx4 wy1v = *(const floatx4*)(sh.wyb + 1 * 64 + w * 16 + quad * 4);
            const floatx4 wy2  = *(const floatx4*)(sh.wyb + 2 * 64 + w * 16 + quad * 4);

            half4 h1p;
            #pragma unroll
            for (int r = 0; r < 4; ++r) {
                const float ig = fmaf(ycur, wy0[r],  t0[r]);
                const float gg = fmaf(ycur, wy1v[r], t1[r]);
                const float og = fmaf(ycur, wy2[r],  t2[r]);
                h1p[r] = (_Float16)lstm_h(ig, gg, og);
            }
            // XOR-swizzled slab write: unit 16B-block = 2*w + (quad>>1)
            {
                const int xblk = (2 * w + (quad >> 1)) ^ (ln & 7);
                *(half4*)(&sh.slab[ln * 64 + xblk * 8 + (quad & 1) * 4]) = h1p;
            }
            __syncthreads();

            // layer 2: A = h1 series-frag (swizzled reads)
            const half8 a0 = *(const half8*)(&sh.slab[ln * 64 + ((quad ^ (ln & 7)) << 3)]);
            const half8 a1 = *(const half8*)(&sh.slab[ln * 64 + (((4 + quad) ^ (ln & 7)) << 3)]);
            floatx4 acc[3];
            #pragma unroll
            for (int j = 0; j < 3; ++j) {
                acc[j] = (floatx4){bias2[j], bias2[j], bias2[j], bias2[j]};
                acc[j] = __builtin_amdgcn_mfma_f32_16x16x32_f16(a0, B2[j][0], acc[j], 0, 0, 0);
                acc[j] = __builtin_amdgcn_mfma_f32_16x16x32_f16(a1, B2[j][1], acc[j], 0, 0, 0);
            }

            // act L2 + head partials: unit w*16+ln, series quad*4+r
            float pmr[4], psr[4];
            #pragma unroll
            for (int r = 0; r < 4; ++r) {
                const float hh = lstm_h(acc[0][r], acc[1][r], acc[2][r]);
                const float hr = fmaxf(hh, 0.0f);
                pmr[r] = hr * wmu;
                psr[r] = hr * wsg;
            }
            #pragma unroll
            for (int off = 1; off < 16; off <<= 1) {
                #pragma unroll
                for (int r = 0; r < 4; ++r) {
                    pmr[r] += __shfl_xor(pmr[r], off, 64);
                    psr[r] += __shfl_xor(psr[r], off, 64);
                }
            }
            if (ln == 0) {
                #pragma unroll
                for (int r = 0; r < 4; ++r) {
                    sh.partm[quad * 4 + r][w] = pmr[r];
                    sh.parts[quad * 4 + r][w] = psr[r];
                }
            }
            __syncthreads();
        }
        return;
    }

    // ======================= teacher-forced path (4 waves) =======================
    // No LDS, no barriers: weights stream from L1/L2 (all blocks share 36 KB).
    const int w    = tid >> 6;
    const int lane = tid & 63;
    const int quad = lane >> 4;
    const int ln   = lane & 15;
    const int cid  = (blockIdx.x - NB_B) * 64 + w * 16 + ln;

    // x fragment for inst=ln, k-chunk quad
    half8 xfr;
    {
        const float* xp = X + (size_t)cid * F_INP + quad * 8;
        xfr = cvt8(*(const float4*)xp, *(const float4*)(xp + 4));
    }
    const float yv = y[cid];

    // L0: outputs written STRAIGHT into the L1 B-fragments (pi-permuted weights
    // make the lane's own 16 h1 values its fragment; zero cross-lane exchange).
    half8 a0, a1;
    {
        const _Float16* bp = W16f + quad * 1536 + ln * 8;      // (kb=quad)*192 rows
        #pragma unroll
        for (int jt = 0; jt < 4; ++jt) {
            // bias init straight from b1c (f32, prescaled, embed-bias folded)
            floatx4 ai = *(const floatx4*)(b1c + jt * 16 + quad * 4);
            floatx4 ag = *(const floatx4*)(b1c + 64 + jt * 16 + quad * 4);
            floatx4 ao = *(const floatx4*)(b1c + 128 + jt * 16 + quad * 4);
            ai = __builtin_amdgcn_mfma_f32_16x16x32_f16(*(const half8*)(bp + jt * 128),        xfr, ai, 0, 0, 0);
            ag = __builtin_amdgcn_mfma_f32_16x16x32_f16(*(const half8*)(bp + 512 + jt * 128),  xfr, ag, 0, 0, 0);
            ao = __builtin_amdgcn_mfma_f32_16x16x32_f16(*(const half8*)(bp + 1024 + jt * 128), xfr, ao, 0, 0, 0);
            // rank-1 y fold (f32)
            const floatx4 wyi = *(const floatx4*)(wy1 + jt * 16 + quad * 4);
            const floatx4 wyg = *(const floatx4*)(wy1 + 64 + jt * 16 + quad * 4);
            const floatx4 wyo = *(const floatx4*)(wy1 + 128 + jt * 16 + quad * 4);
            // r = 0..3 -> hid = jt*16 + quad*4 + r; pi places (r0,r1) -> a0[2jt..],
            // (r2,r3) -> a1[2jt..]
            a0[2 * jt + 0] = (_Float16)lstm_h(fmaf(yv, wyi[0], ai[0]),
                                              fmaf(yv, wyg[0], ag[0]),
                                              fmaf(yv, wyo[0], ao[0]));
            a0[2 * jt + 1] = (_Float16)lstm_h(fmaf(yv, wyi[1], ai[1]),
                                              fmaf(yv, wyg[1], ag[1]),
                                              fmaf(yv, wyo[1], ao[1]));
            a1[2 * jt + 0] = (_Float16)lstm_h(fmaf(yv, wyi[2], ai[2]),
                                              fmaf(yv, wyg[2], ag[2]),
                                              fmaf(yv, wyo[2], ao[2]));
            a1[2 * jt + 1] = (_Float16)lstm_h(fmaf(yv, wyi[3], ai[3]),
                                              fmaf(yv, wyg[3], ag[3]),
                                              fmaf(yv, wyo[3], ao[3]));
        }
    }

    float pm = 0.f, ps = 0.f;
    {
        const _Float16* bp = W16f + W16F_L1P + quad * 1536 + ln * 8;
        #pragma unroll
        for (int jt = 0; jt < 4; ++jt) {
            floatx4 ai = *(const floatx4*)(bsum + NROW + jt * 16 + quad * 4);
            floatx4 ag = *(const floatx4*)(bsum + NROW + 64 + jt * 16 + quad * 4);
            floatx4 ao = *(const floatx4*)(bsum + NROW + 128 + jt * 16 + quad * 4);
            ai = __builtin_amdgcn_mfma_f32_16x16x32_f16(*(const half8*)(bp + jt * 128),               a0, ai, 0, 0, 0);
            ai = __builtin_amdgcn_mfma_f32_16x16x32_f16(*(const half8*)(bp + 6144 + jt * 128),        a1, ai, 0, 0, 0);
            ag = __builtin_amdgcn_mfma_f32_16x16x32_f16(*(const half8*)(bp + 512 + jt * 128),         a0, ag, 0, 0, 0);
            ag = __builtin_amdgcn_mfma_f32_16x16x32_f16(*(const half8*)(bp + 6144 + 512 + jt * 128),  a1, ag, 0, 0, 0);
            ao = __builtin_amdgcn_mfma_f32_16x16x32_f16(*(const half8*)(bp + 1024 + jt * 128),        a0, ao, 0, 0, 0);
            ao = __builtin_amdgcn_mfma_f32_16x16x32_f16(*(const half8*)(bp + 6144 + 1024 + jt * 128), a1, ao, 0, 0, 0);
            // head partials in-thread: rows hid = jt*16+quad*4+r, inst = ln
            const floatx4 wm  = *(const floatx4*)(W_mu + jt * 16 + quad * 4);
            const floatx4 ws4 = *(const floatx4*)(W_sigma + jt * 16 + quad * 4);
            #pragma unroll
            for (int r = 0; r < 4; ++r) {
                const float hr = fmaxf(lstm_h(ai[r], ag[r], ao[r]), 0.0f);
                pm = fmaf(hr, wm[r], pm);
                ps = fmaf(hr, ws4[r], ps);
            }
        }
    }
    // reduce over quads only (hid split across quads; inst=ln is lane-local)
    pm += __shfl_xor(pm, 16, 64); pm += __shfl_xor(pm, 32, 64);
    ps += __shfl_xor(ps, 16, 64); ps += __shfl_xor(ps, 32, 64);

    if (quad == 0) {
        const int n = cid / SEQ;
        const int t = cid - n * SEQ;
        const float mu = pm + b_mu[0];
        const float sg = softplus_(ps + b_sigma[0]) + 1e-6f;
        mu_out[(size_t)n * T_ALL + t] = mu;
        sg_out[(size_t)n * T_ALL + t] = sg;
        if (t == SEQ - 1) {
            const float d  = yv - mu;
            const float is = frcp(sg);
            out[(size_t)n * HOR] = 0.39894228040143267f * is * fexp(-0.5f * d * d * is * is);
        }
    }
}

extern "C" void kernel_launch(void* const* d_in, const int* in_sizes, int n_in,
                              void* d_out, int out_size, void* d_ws, size_t ws_size,
                              hipStream_t stream) {
    const float* X       = (const float*)d_in[0];
    const float* y       = (const float*)d_in[1];
    const float* Xf      = (const float*)d_in[2];
    const float* W_embed = (const float*)d_in[3];
    const float* b_embed = (const float*)d_in[4];
    const float* W_ih    = (const float*)d_in[5];
    const float* b_ih    = (const float*)d_in[6];
    const float* b_hh    = (const float*)d_in[7];
    const float* W_mu    = (const float*)d_in[8];
    const float* b_mu    = (const float*)d_in[9];
    const float* W_sigma = (const float*)d_in[10];
    const float* b_sigma = (const float*)d_in[11];

    float* out = (float*)d_out;
    // ws: W16f(61440 B: L0 12KB + L1std 24KB + L1perm 24KB) | bsum(1536) | wy1(768) | b1c(768)
    _Float16*  W16f = (_Float16*)d_ws;
    float*     bsum = (float*)((char*)d_ws + 61440);
    float*     wy1  = (float*)((char*)d_ws + 61440 + 1536);
    float*     b1c  = (float*)((char*)d_ws + 61440 + 1536 + 768);

    prep<<<96, 256, 0, stream>>>(W_ih, b_ih, b_hh, W_embed, b_embed,
                                 W16f, bsum, wy1, b1c);

    fused<<<NB_B + NT_B, 256, 0, stream>>>(
        X, y, Xf, W_embed, b_embed, W16f, bsum, wy1, b1c,
        W_mu, b_mu, W_sigma, b_sigma, out);
}

// Round 5
// 249.547 us; speedup vs baseline: 1.1052x; 1.1052x over previous
//
#include <hip/hip_runtime.h>
#include <math.h>

#define N_TS 4096
#define SEQ  168
#define HOR  24
#define T_ALL 192
#define F_INP 32
#define HID  64
#define NROW 192            // compacted gate rows: i(64) g(64) o(64)
#define NB_B (N_TS / 16)    // 256 autoregressive blocks (16 series each)
#define NT_B ((N_TS * SEQ) / 64)   // 10752 teacher blocks (64 instances each)
#define L2E  1.44269504089f
#define W16F_L1  6144       // half-offset of standard layer-1 weights (AR path)
#define W16F_L1P 18432      // half-offset of PHASE-MAJOR permuted layer-1 weights

typedef _Float16 half8  __attribute__((ext_vector_type(8)));
typedef _Float16 half4  __attribute__((ext_vector_type(4)));
typedef float    floatx4 __attribute__((ext_vector_type(4)));

__device__ __forceinline__ float fexp(float x)  { return __expf(x); }
__device__ __forceinline__ float ex2(float x)   { return __builtin_amdgcn_exp2f(x); }
__device__ __forceinline__ float frcp(float x)  { return __builtin_amdgcn_rcpf(x); }
__device__ __forceinline__ float softplus_(float x) { return (x > 15.0f) ? x : __logf(1.0f + fexp(x)); }

// Gates arrive PRESCALED: i,o rows x(-log2e); g rows x(-2*log2e) — folded into
// weights/biases, so every sigmoid/tanh exp is a bare v_exp (2^x).
__device__ __forceinline__ float lstm_h(float ip, float gp, float op) {
    const float Ei = ex2(ip);
    const float Eg = ex2(gp);
    const float cc = (1.0f - Eg) * frcp((1.0f + Ei) * (1.0f + Eg));
    const float Ec = ex2(cc * (-2.0f * L2E));
    const float Eo = ex2(op);
    return (1.0f - Ec) * frcp((1.0f + Ec) * (1.0f + Eo));
}

__device__ __forceinline__ half8 cvt8(const float4 a, const float4 b) {
    half8 v;
    v[0]=(_Float16)a.x; v[1]=(_Float16)a.y; v[2]=(_Float16)a.z; v[3]=(_Float16)a.w;
    v[4]=(_Float16)b.x; v[5]=(_Float16)b.y; v[6]=(_Float16)b.z; v[7]=(_Float16)b.w;
    return v;
}

// ---------------------------------------------------------------------------
// prep: compacted (f dropped), PRESCALED weights in k-chunked fragment layout
//   layer 0 (x-cols only, k<32): W16f[(kb*192+row)*8+kp], kb in [0,4)
//   layer 1 standard (AR path):  W16f[W16F_L1 + (kb*192+row)*8+kp], k = hid
//   layer 1 permuted PHASE-MAJOR (teacher): W16F_L1P +
//       h*6144 + ((kb*96 + gate*32 + jtl*16 + r16)*8 + kp), jt = h*2+jtl,
//     column k = pi(hid):  k=q*8+2*d+e     <-> hid=d*16+q*4+e      (k < 32)
//                          k=32+q*8+2*d+e  <-> hid=d*16+q*4+2+e    (k >= 32)
//   so the teacher's own L0 output registers ARE its L1 B-fragment (no exchange),
//   and each 12 KB phase-half is self-contained (all gates, both k-halves).
// Rank-1 embed fold (prescaled): wy1 = W1[:,32:]@W_embed ; b1c = b1 + W1[:,32:]@b_embed.
// ---------------------------------------------------------------------------
__global__ __launch_bounds__(256) void prep(
    const float* __restrict__ W_ih, const float* __restrict__ b_ih,
    const float* __restrict__ b_hh,
    const float* __restrict__ W_embed, const float* __restrict__ b_embed,
    _Float16* __restrict__ W16f, float* __restrict__ bsum,
    float* __restrict__ wy1, float* __restrict__ b1c)
{
    const int idx = blockIdx.x * 256 + threadIdx.x;
    // layer 0: x-cols only
    for (int i = idx; i < 4 * NROW * 8; i += gridDim.x * 256) {
        const int kp  = i & 7;
        const int row = (i >> 3) % NROW;
        const int kb  = (i >> 3) / NROW;                   // 0..3 -> k = kb*8+kp < 32
        const int sr  = (row < 64) ? row : row + 64;       // skip dead f rows
        const float sc = (row >= 64 && row < 128) ? (-2.0f * L2E) : (-L2E);
        W16f[i] = (_Float16)(W_ih[sr * HID + kb * 8 + kp] * sc);
    }
    // layer 1 standard (k = hid identity) — AR path
    for (int i = idx; i < 8 * NROW * 8; i += gridDim.x * 256) {
        const int kp  = i & 7;
        const int row = (i >> 3) % NROW;
        const int kb  = (i >> 3) / NROW;                   // 0..7
        const int sr  = (row < 64) ? row : row + 64;
        const float sc = (row >= 64 && row < 128) ? (-2.0f * L2E) : (-L2E);
        W16f[W16F_L1 + i] = (_Float16)(W_ih[(256 + sr) * HID + kb * 8 + kp] * sc);
    }
    // layer 1 permuted, phase-major (teacher)
    for (int i = idx; i < 2 * 6144; i += gridDim.x * 256) {
        const int h    = i / 6144;
        const int rem  = i - h * 6144;
        const int kp   = rem & 7;
        const int t    = rem >> 3;                         // 0..767
        const int rowb = t % 96;
        const int kb   = t / 96;                           // 0..7
        const int gate = rowb >> 5;                        // 0:i 1:g 2:o
        const int jtl  = (rowb >> 4) & 1;
        const int r16  = rowb & 15;
        const int jt   = h * 2 + jtl;
        const int srow = gate * 64 + jt * 16 + r16;        // compacted row 0..191
        const int sr   = (srow < 64) ? srow : srow + 64;   // skip dead f rows
        const int k    = kb * 8 + kp;                      // logical k = pi(hid)
        const int kk   = k & 31;
        const int d    = (kk >> 1) & 3;
        const int q    = kk >> 3;
        const int e    = kk & 1;
        const int hid  = d * 16 + q * 4 + ((k >> 5) << 1) + e;
        const float sc = (gate == 1) ? (-2.0f * L2E) : (-L2E);
        W16f[W16F_L1P + i] = (_Float16)(W_ih[(256 + sr) * HID + hid] * sc);
    }
    for (int i = idx; i < 2 * NROW; i += gridDim.x * 256) {
        const int r = i % NROW;
        const int l = i / NROW;
        const int sr = (r < 64) ? r : r + 64;
        const float sc = (r >= 64 && r < 128) ? (-2.0f * L2E) : (-L2E);
        bsum[i] = (b_ih[l * 256 + sr] + b_hh[l * 256 + sr]) * sc;
    }
    if (idx < NROW) {
        const int sr = (idx < 64) ? idx : idx + 64;
        const float sc = (idx >= 64 && idx < 128) ? (-2.0f * L2E) : (-L2E);
        const float* wrow = W_ih + sr * HID + 32;          // layer 0, cols 32..63
        float s1 = 0.f, s2 = 0.f;
        #pragma unroll
        for (int k = 0; k < 32; ++k) {
            s1 = fmaf(wrow[k], W_embed[k], s1);
            s2 = fmaf(wrow[k], b_embed[k], s2);
        }
        wy1[idx] = s1 * sc;
        b1c[idx] = (b_ih[sr] + b_hh[sr] + s2) * sc;
    }
}

// ---------------------------------------------------------------------------
// fused, 256-thread blocks (4 waves):
//  blocks [0, NB_B): autoregressive path — proven 16-series form, persistent
//   register fragments, XOR-swizzled slab, 2 barriers/step. Unchanged (r3).
//  blocks [NB_B, ...): teacher path with 12 KB LDS staging in 3 phases:
//   stage L0 (12K) -> compute L0 (h1 lives in registers via pi-permuted
//   weights) -> stage L1P half0 (jt 0,1) -> compute -> stage half1 -> compute.
//  LDS union = 12288 B -> 8 blocks/CU (32 waves/CU, 100% wave ceiling)
//  at VGPR=40 (runtime occupancy is resource-determined; bounds stay (256,6)).
// ---------------------------------------------------------------------------
__global__ __launch_bounds__(256, 6) void fused(
    const float* __restrict__ X,
    const float* __restrict__ y,
    const float* __restrict__ Xf,
    const float* __restrict__ W_embed,
    const float* __restrict__ b_embed,
    const _Float16* __restrict__ W16f,
    const float* __restrict__ bsum,
    const float* __restrict__ wy1,
    const float* __restrict__ b1c,
    const float* __restrict__ W_mu,
    const float* __restrict__ b_mu,
    const float* __restrict__ W_sigma,
    const float* __restrict__ b_sigma,
    float* __restrict__ out)
{
    __shared__ union __align__(16) {
        struct { _Float16 Wl[6144]; } A;                                 // 12288 B
        struct { _Float16 slab[16 * 64]; float partm[16][4]; float parts[16][4];
                 float wyb[NROW]; float b1cb[NROW]; } B;                 // ~4.1 KB
    } sh;

    const int tid = threadIdx.x;
    float* mu_out = out + (size_t)N_TS * HOR;
    float* sg_out = mu_out + (size_t)N_TS * T_ALL;

    if (blockIdx.x < NB_B) {
        // =================== autoregressive path (4 waves) ===================
        __builtin_amdgcn_s_setprio(1);           // beat co-resident teacher waves
        const int w    = tid >> 6;
        const int lane = tid & 63;
        const int quad = lane >> 4;
        const int ln   = lane & 15;
        const int n0   = blockIdx.x * 16;

        if (tid < NROW) {
            sh.B.wyb[tid]  = wy1[tid];
            sh.B.b1cb[tid] = b1c[tid];
        }

        // persistent register fragments (wave w owns row-tiles rt = j*4+w)
        half8 B1[3];        // W1 rows, k<32 (embed cols via rank-1 fold)
        half8 B2[3][2];     // W2 rows, full k (STANDARD layout)
        float bias2[3];
        #pragma unroll
        for (int j = 0; j < 3; ++j) {
            const int rt = j * 4 + w;
            B1[j] = *(const half8*)(W16f + ((size_t)quad * NROW + rt * 16 + ln) * 8);
            #pragma unroll
            for (int kt = 0; kt < 2; ++kt)
                B2[j][kt] = *(const half8*)(W16f + W16F_L1 + ((size_t)(kt * 4 + quad) * NROW + rt * 16 + ln) * 8);
            bias2[j] = bsum[NROW + rt * 16 + ln];
        }
        const float wmu = W_mu[w * 16 + ln], wsg = W_sigma[w * 16 + ln];
        const float bmu = b_mu[0], bsg = b_sigma[0];

        // bootstrap inputs: t = 167
        const float* xfp = Xf + (size_t)(n0 + ln) * HOR * F_INP + quad * 8;
        float4 xa, xb;
        {
            const float* xp = X + ((size_t)(n0 + ln) * SEQ + (SEQ - 1)) * F_INP + quad * 8;
            xa = *(const float4*)xp;
            xb = *(const float4*)(xp + 4);
        }
        float ycur = y[(size_t)(n0 + ln) * SEQ + (SEQ - 1)];
        __syncthreads();                         // wyb/b1cb visible

        #pragma unroll 1
        for (int it = 0; it <= HOR + 1; ++it) {
            if (it > 0) {
                // finalize step k = it-1 (redundant per-lane, bit-identical)
                const int k = it - 1;
                const float4 m4 = *(const float4*)sh.B.partm[ln];
                const float4 s4 = *(const float4*)sh.B.parts[ln];
                const float mu = (m4.x + m4.y) + (m4.z + m4.w) + bmu;
                const float sg = softplus_((s4.x + s4.y) + (s4.z + s4.w) + bsg) + 1e-6f;
                const float d  = ycur - mu;
                const float is = frcp(sg);
                const float lik = 0.39894228040143267f * is * fexp(-0.5f * d * d * is * is);
                if (k > 0 && w == 0 && quad == 0) {
                    const int nn = n0 + ln;
                    const int t  = SEQ + k - 1;
                    mu_out[(size_t)nn * T_ALL + t] = mu;
                    sg_out[(size_t)nn * T_ALL + t] = sg;
                    if (k < HOR) out[(size_t)nn * HOR + k] = lik;
                }
                ycur = lik;
            }
            if (it > HOR) break;

            // ---- compute step it (input carry = ycur) ----
            const half8 xf0 = cvt8(xa, xb);
            if (it < HOR) {                      // next iter uses Xf step it
                xa = *(const float4*)(xfp + it * F_INP);
                xb = *(const float4*)(xfp + it * F_INP + 4);
            }

            // layer 1: 3 MFMAs; C row = unit-in-tile (quad*4+r), col = series(ln)
            floatx4 t0 = *(const floatx4*)(sh.B.b1cb + 0 * 64 + w * 16 + quad * 4);
            floatx4 t1 = *(const floatx4*)(sh.B.b1cb + 1 * 64 + w * 16 + quad * 4);
            floatx4 t2 = *(const floatx4*)(sh.B.b1cb + 2 * 64 + w * 16 + quad * 4);
            t0 = __builtin_amdgcn_mfma_f32_16x16x32_f16(B1[0], xf0, t0, 0, 0, 0);
            t1 = __builtin_amdgcn_mfma_f32_16x16x32_f16(B1[1], xf0, t1, 0, 0, 0);
            t2 = __builtin_amdgcn_mfma_f32_16x16x32_f16(B1[2], xf0, t2, 0, 0, 0);

            const floatx4 wy0  = *(const floatx4*)(sh.B.wyb + 0 * 64 + w * 16 + quad * 4);
            const floatx4 wy1v = *(const floatx4*)(sh.B.wyb + 1 * 64 + w * 16 + quad * 4);
            const floatx4 wy2  = *(const floatx4*)(sh.B.wyb + 2 * 64 + w * 16 + quad * 4);

            half4 h1p;
            #pragma unroll
            for (int r = 0; r < 4; ++r) {
                const float ig = fmaf(ycur, wy0[r],  t0[r]);
                const float gg = fmaf(ycur, wy1v[r], t1[r]);
                const float og = fmaf(ycur, wy2[r],  t2[r]);
                h1p[r] = (_Float16)lstm_h(ig, gg, og);
            }
            // XOR-swizzled slab write: unit 16B-block = 2*w + (quad>>1)
            {
                const int xblk = (2 * w + (quad >> 1)) ^ (ln & 7);
                *(half4*)(&sh.B.slab[ln * 64 + xblk * 8 + (quad & 1) * 4]) = h1p;
            }
            __syncthreads();

            // layer 2: A = h1 series-frag (swizzled reads)
            const half8 a0 = *(const half8*)(&sh.B.slab[ln * 64 + ((quad ^ (ln & 7)) << 3)]);
            const half8 a1 = *(const half8*)(&sh.B.slab[ln * 64 + (((4 + quad) ^ (ln & 7)) << 3)]);
            floatx4 acc[3];
            #pragma unroll
            for (int j = 0; j < 3; ++j) {
                acc[j] = (floatx4){bias2[j], bias2[j], bias2[j], bias2[j]};
                acc[j] = __builtin_amdgcn_mfma_f32_16x16x32_f16(a0, B2[j][0], acc[j], 0, 0, 0);
                acc[j] = __builtin_amdgcn_mfma_f32_16x16x32_f16(a1, B2[j][1], acc[j], 0, 0, 0);
            }

            // act L2 + head partials: unit w*16+ln, series quad*4+r
            float pmr[4], psr[4];
            #pragma unroll
            for (int r = 0; r < 4; ++r) {
                const float hh = lstm_h(acc[0][r], acc[1][r], acc[2][r]);
                const float hr = fmaxf(hh, 0.0f);
                pmr[r] = hr * wmu;
                psr[r] = hr * wsg;
            }
            #pragma unroll
            for (int off = 1; off < 16; off <<= 1) {
                #pragma unroll
                for (int r = 0; r < 4; ++r) {
                    pmr[r] += __shfl_xor(pmr[r], off, 64);
                    psr[r] += __shfl_xor(psr[r], off, 64);
                }
            }
            if (ln == 0) {
                #pragma unroll
                for (int r = 0; r < 4; ++r) {
                    sh.B.partm[quad * 4 + r][w] = pmr[r];
                    sh.B.parts[quad * 4 + r][w] = psr[r];
                }
            }
            __syncthreads();
        }
        return;
    }

    // ======================= teacher-forced path (4 waves) =======================
    const int w    = tid >> 6;
    const int lane = tid & 63;
    const int quad = lane >> 4;
    const int ln   = lane & 15;
    const int cid  = (blockIdx.x - NB_B) * 64 + w * 16 + ln;

    // x fragment for inst=ln, k-chunk quad
    half8 xfr;
    {
        const float* xp = X + (size_t)cid * F_INP + quad * 8;
        xfr = cvt8(*(const float4*)xp, *(const float4*)(xp + 4));
    }
    const float yv = y[cid];

    // ---- stage layer-0 weights (6144 halfs = 12 KB) ----
    #pragma unroll
    for (int c = 0; c < 3; ++c) {
        const int off = (c * 256 + tid) * 8;
        *(half8*)(sh.A.Wl + off) = *(const half8*)(W16f + off);
    }
    __syncthreads();

    // L0: outputs written STRAIGHT into the L1 B-fragments (pi-permuted weights
    // make the lane's own 16 h1 values its fragment; zero cross-lane exchange).
    half8 a0, a1;
    {
        const _Float16* bp = sh.A.Wl + quad * 1536 + ln * 8;   // (kb=quad)*192 rows
        #pragma unroll
        for (int jt = 0; jt < 4; ++jt) {
            // bias init straight from b1c (f32, prescaled, embed-bias folded)
            floatx4 ai = *(const floatx4*)(b1c + jt * 16 + quad * 4);
            floatx4 ag = *(const floatx4*)(b1c + 64 + jt * 16 + quad * 4);
            floatx4 ao = *(const floatx4*)(b1c + 128 + jt * 16 + quad * 4);
            ai = __builtin_amdgcn_mfma_f32_16x16x32_f16(*(const half8*)(bp + jt * 128),        xfr, ai, 0, 0, 0);
            ag = __builtin_amdgcn_mfma_f32_16x16x32_f16(*(const half8*)(bp + 512 + jt * 128),  xfr, ag, 0, 0, 0);
            ao = __builtin_amdgcn_mfma_f32_16x16x32_f16(*(const half8*)(bp + 1024 + jt * 128), xfr, ao, 0, 0, 0);
            // rank-1 y fold (f32)
            const floatx4 wyi = *(const floatx4*)(wy1 + jt * 16 + quad * 4);
            const floatx4 wyg = *(const floatx4*)(wy1 + 64 + jt * 16 + quad * 4);
            const floatx4 wyo = *(const floatx4*)(wy1 + 128 + jt * 16 + quad * 4);
            // r = 0..3 -> hid = jt*16 + quad*4 + r; pi places (r0,r1) -> a0[2jt..],
            // (r2,r3) -> a1[2jt..]
            a0[2 * jt + 0] = (_Float16)lstm_h(fmaf(yv, wyi[0], ai[0]),
                                              fmaf(yv, wyg[0], ag[0]),
                                              fmaf(yv, wyo[0], ao[0]));
            a0[2 * jt + 1] = (_Float16)lstm_h(fmaf(yv, wyi[1], ai[1]),
                                              fmaf(yv, wyg[1], ag[1]),
                                              fmaf(yv, wyo[1], ao[1]));
            a1[2 * jt + 0] = (_Float16)lstm_h(fmaf(yv, wyi[2], ai[2]),
                                              fmaf(yv, wyg[2], ag[2]),
                                              fmaf(yv, wyo[2], ao[2]));
            a1[2 * jt + 1] = (_Float16)lstm_h(fmaf(yv, wyi[3], ai[3]),
                                              fmaf(yv, wyg[3], ag[3]),
                                              fmaf(yv, wyo[3], ao[3]));
        }
    }
    __syncthreads();                 // all Wl(L0) reads done

    // ---- L1 in two 12 KB phases: phase h covers jt = 2h, 2h+1 ----
    float pm = 0.f, ps = 0.f;
    #pragma unroll
    for (int h = 0; h < 2; ++h) {
        #pragma unroll
        for (int c = 0; c < 3; ++c) {
            const int off = (c * 256 + tid) * 8;
            *(half8*)(sh.A.Wl + off) = *(const half8*)(W16f + W16F_L1P + h * 6144 + off);
        }
        __syncthreads();
        const _Float16* bp = sh.A.Wl + quad * 768 + ln * 8;    // kb=quad block (96 rows)
        #pragma unroll
        for (int jtl = 0; jtl < 2; ++jtl) {
            const int jt = h * 2 + jtl;
            floatx4 ai = *(const floatx4*)(bsum + NROW + jt * 16 + quad * 4);
            floatx4 ag = *(const floatx4*)(bsum + NROW + 64 + jt * 16 + quad * 4);
            floatx4 ao = *(const floatx4*)(bsum + NROW + 128 + jt * 16 + quad * 4);
            ai = __builtin_amdgcn_mfma_f32_16x16x32_f16(*(const half8*)(bp + jtl * 128),               a0, ai, 0, 0, 0);
            ai = __builtin_amdgcn_mfma_f32_16x16x32_f16(*(const half8*)(bp + jtl * 128 + 3072),        a1, ai, 0, 0, 0);
            ag = __builtin_amdgcn_mfma_f32_16x16x32_f16(*(const half8*)(bp + 256 + jtl * 128),         a0, ag, 0, 0, 0);
            ag = __builtin_amdgcn_mfma_f32_16x16x32_f16(*(const half8*)(bp + 256 + jtl * 128 + 3072),  a1, ag, 0, 0, 0);
            ao = __builtin_amdgcn_mfma_f32_16x16x32_f16(*(const half8*)(bp + 512 + jtl * 128),         a0, ao, 0, 0, 0);
            ao = __builtin_amdgcn_mfma_f32_16x16x32_f16(*(const half8*)(bp + 512 + jtl * 128 + 3072),  a1, ao, 0, 0, 0);
            // head partials in-thread: rows hid = jt*16+quad*4+r, inst = ln
            const floatx4 wm  = *(const floatx4*)(W_mu + jt * 16 + quad * 4);
            const floatx4 ws4 = *(const floatx4*)(W_sigma + jt * 16 + quad * 4);
            #pragma unroll
            for (int r = 0; r < 4; ++r) {
                const float hr = fmaxf(lstm_h(ai[r], ag[r], ao[r]), 0.0f);
                pm = fmaf(hr, wm[r], pm);
                ps = fmaf(hr, ws4[r], ps);
            }
        }
        __syncthreads();             // phase reads done before next stage / exit
    }

    // reduce over quads only (hid split across quads; inst=ln is lane-local)
    pm += __shfl_xor(pm, 16, 64); pm += __shfl_xor(pm, 32, 64);
    ps += __shfl_xor(ps, 16, 64); ps += __shfl_xor(ps, 32, 64);

    if (quad == 0) {
        const int n = cid / SEQ;
        const int t = cid - n * SEQ;
        const float mu = pm + b_mu[0];
        const float sg = softplus_(ps + b_sigma[0]) + 1e-6f;
        mu_out[(size_t)n * T_ALL + t] = mu;
        sg_out[(size_t)n * T_ALL + t] = sg;
        if (t == SEQ - 1) {
            const float d  = yv - mu;
            const float is = frcp(sg);
            out[(size_t)n * HOR] = 0.39894228040143267f * is * fexp(-0.5f * d * d * is * is);
        }
    }
}

extern "C" void kernel_launch(void* const* d_in, const int* in_sizes, int n_in,
                              void* d_out, int out_size, void* d_ws, size_t ws_size,
                              hipStream_t stream) {
    const float* X       = (const float*)d_in[0];
    const float* y       = (const float*)d_in[1];
    const float* Xf      = (const float*)d_in[2];
    const float* W_embed = (const float*)d_in[3];
    const float* b_embed = (const float*)d_in[4];
    const float* W_ih    = (const float*)d_in[5];
    const float* b_ih    = (const float*)d_in[6];
    const float* b_hh    = (const float*)d_in[7];
    const float* W_mu    = (const float*)d_in[8];
    const float* b_mu    = (const float*)d_in[9];
    const float* W_sigma = (const float*)d_in[10];
    const float* b_sigma = (const float*)d_in[11];

    float* out = (float*)d_out;
    // ws: W16f(61440 B: L0 12KB + L1std 24KB + L1perm 24KB) | bsum(1536) | wy1(768) | b1c(768)
    _Float16*  W16f = (_Float16*)d_ws;
    float*     bsum = (float*)((char*)d_ws + 61440);
    float*     wy1  = (float*)((char*)d_ws + 61440 + 1536);
    float*     b1c  = (float*)((char*)d_ws + 61440 + 1536 + 768);

    prep<<<96, 256, 0, stream>>>(W_ih, b_ih, b_hh, W_embed, b_embed,
                                 W16f, bsum, wy1, b1c);

    fused<<<NB_B + NT_B, 256, 0, stream>>>(
        X, y, Xf, W_embed, b_embed, W16f, bsum, wy1, b1c,
        W_mu, b_mu, W_sigma, b_sigma, out);
}